// Round 9
// baseline (152.350 us; speedup 1.0000x reference)
//
#include <hip/hip_runtime.h>

#define BATCH 64
#define MM 512
#define NN 512
#define DDIM 64

#define K2E   14.426950408889634f     // log2(e)/gamma, gamma=0.1
#define GLN2  0.06931471805599453f    // gamma*ln(2)
#define NEGB  (-1.4426950e11f)        // t-domain encoding of R=BIG=1e10

typedef __attribute__((ext_vector_type(8))) short short8;    // 8 bf16 (4 VGPR)
typedef __attribute__((ext_vector_type(4))) float floatx4;   // MFMA acc
typedef __attribute__((ext_vector_type(4))) unsigned int uintx4;

__device__ __forceinline__ unsigned short f2bf(float f) {
    unsigned int u = __float_as_uint(f);
    unsigned int r = (u + 0x7FFFu + ((u >> 16) & 1u)) >> 16;   // RNE
    return (unsigned short)r;
}

// Step-major compact layout, bf16 elements. Block s (=tg+m, s in [0,191))
// holds all tiles consumed at DP step s, ordered [tslot][c in 4][r in 8]
// (ushort idx within block = tslot*32 + c*8 + r).
__device__ __forceinline__ int q_cnt(int s)  { return s < 64 ? s + 1 : (s < 128 ? 64 : 191 - s); }
__device__ __forceinline__ int q_tb(int s)   { return s < 128 ? 0 : s - 127; }
__device__ __forceinline__ int q_pre(int s)  {
    return s < 64 ? ((s * (s + 1)) >> 1)
         : (s < 128 ? 2080 + ((s - 64) << 6)
                    : 8192 - (((191 - s) * (192 - s)) >> 1));
}

// ---------------------------------------------------------------------------
// Kernel 1 (MFMA): t-domain D' = min(0, 2*K2E*G - K2E|x|^2 - K2E|y|^2),
// single-bf16 Gram, bf16 P (round-8 verified). ONLY change vs round 8:
// STORE PATH. The MFMA epilogue's uint2 results go to a 32KB LDS tile
// SP[tgl 16][ml 32][16 words] (identical bytes), then after a barrier a
// cooperative write-out emits the 47 s-pieces of this block as contiguous
// dwordx4 runs (1KB/wave-instr) — replacing 4096 scattered 8B stores/block
// (~28 cache lines per wave-instr, the suspected K1 bottleneck).
// P contents bit-identical to round 8.
// ---------------------------------------------------------------------------
#define LDSTRU 36   // uints per LDS row (72 bf16 = 64 + 8 pad; 144 B, 16B-aligned)
__global__ __launch_bounds__(256) void compute_d_kernel(const float* __restrict__ x,
                                                        const float* __restrict__ y,
                                                        float* __restrict__ P) {
    __shared__ unsigned int xhiW[128 * LDSTRU];
    __shared__ unsigned int yhiW[128 * LDSTRU];
    __shared__ float xnk[128], ynk[128];
    __shared__ unsigned int SP[16 * 32 * 16];   // 32 KB staged P-tile

    const int b  = blockIdx.z;
    const int i0 = blockIdx.y * 128;
    const int j0 = blockIdx.x * 128;
    const int tid = threadIdx.x;

    const float* xb = x + ((size_t)b * MM + i0) * DDIM;
    const float* yb = y + ((size_t)b * NN + j0) * DDIM;

#pragma unroll
    for (int it = 0; it < 8; ++it) {
        int idx = it * 256 + tid;        // 0..2047 float4-chunks
        int k4  = idx & 15;              // coalesced: 16 lanes cover one row
        int row = idx >> 4;
        float4 vx = *(const float4*)(xb + row * DDIM + k4 * 4);
        float4 vy = *(const float4*)(yb + row * DDIM + k4 * 4);
        int base = row * LDSTRU + k4 * 2;

        unsigned short h0 = f2bf(vx.x), h1 = f2bf(vx.y), h2 = f2bf(vx.z), h3 = f2bf(vx.w);
        xhiW[base]     = (unsigned)h0 | ((unsigned)h1 << 16);
        xhiW[base + 1] = (unsigned)h2 | ((unsigned)h3 << 16);

        h0 = f2bf(vy.x); h1 = f2bf(vy.y); h2 = f2bf(vy.z); h3 = f2bf(vy.w);
        yhiW[base]     = (unsigned)h0 | ((unsigned)h1 << 16);
        yhiW[base + 1] = (unsigned)h2 | ((unsigned)h3 << 16);
    }
    __syncthreads();

    {
        int r = tid & 127;
        const unsigned int* ph = (tid < 128 ? xhiW : yhiW) + r * LDSTRU;
        float s = 0.0f;
#pragma unroll
        for (int kk = 0; kk < 32; ++kk) {
            unsigned int uh = ph[kk];
            float e0 = __uint_as_float(uh << 16);
            float e1 = __uint_as_float(uh & 0xFFFF0000u);
            s = fmaf(e0, e0, s);
            s = fmaf(e1, e1, s);
        }
        if (tid < 128) xnk[r] = K2E * s; else ynk[r] = K2E * s;
    }
    __syncthreads();

    const int wid = tid >> 6, lane = tid & 63;
    const int ln = lane & 15, q = lane >> 4;
    const unsigned short* XH = (const unsigned short*)xhiW;
    const unsigned short* YH = (const unsigned short*)yhiW;

#pragma unroll
    for (int tr2 = 0; tr2 < 2; ++tr2) {
        const int I0 = (wid * 2 + tr2) * 16;
        const int arow = (I0 + ln) * (2 * LDSTRU);
        short8 ah0 = *(const short8*)&XH[arow + q * 8];
        short8 ah1 = *(const short8*)&XH[arow + 32 + q * 8];

        float xnr[4];
#pragma unroll
        for (int reg = 0; reg < 4; ++reg) xnr[reg] = xnk[I0 + q * 4 + reg];

        const int tgl   = (wid * 2 + tr2) * 2 + (q >> 1);  // local tile-row 0..15
        const int rbase = (q & 1) * 4;                     // 0 or 4

#pragma unroll
        for (int tc = 0; tc < 8; ++tc) {
            const int J0 = tc * 16;
            const int brow = (J0 + ln) * (2 * LDSTRU);
            short8 bh0 = *(const short8*)&YH[brow + q * 8];
            short8 bh1 = *(const short8*)&YH[brow + 32 + q * 8];

            floatx4 acc = {0.0f, 0.0f, 0.0f, 0.0f};
            acc = __builtin_amdgcn_mfma_f32_16x16x32_bf16(ah0, bh0, acc, 0, 0, 0);
            acc = __builtin_amdgcn_mfma_f32_16x16x32_bf16(ah1, bh1, acc, 0, 0, 0);

            const float yn = ynk[J0 + ln];
            const int ml = tc * 4 + (ln >> 2);             // local m 0..31
            const int c  = ln & 3;

            float v0 = fminf(fmaf(acc[0], 2.0f * K2E, -xnr[0]) - yn, 0.0f);
            float v1 = fminf(fmaf(acc[1], 2.0f * K2E, -xnr[1]) - yn, 0.0f);
            float v2 = fminf(fmaf(acc[2], 2.0f * K2E, -xnr[2]) - yn, 0.0f);
            float v3 = fminf(fmaf(acc[3], 2.0f * K2E, -xnr[3]) - yn, 0.0f);
            uint2 pk;
            pk.x = (unsigned)f2bf(v0) | ((unsigned)f2bf(v1) << 16);
            pk.y = (unsigned)f2bf(v2) | ((unsigned)f2bf(v3) << 16);
            *(uint2*)&SP[tgl * 512 + ml * 16 + c * 4 + (rbase >> 1)] = pk;
        }
    }
    __syncthreads();

    // ---- coalesced write-out: 47 s-pieces, each a contiguous run of
    //      (tghi-tglo+1) x 64B in the step-major global layout ----
    {
        const int T0 = blockIdx.y * 16;   // global tg base
        const int M0 = blockIdx.x * 32;   // global m base
        unsigned int* Qw = (unsigned int*)P + (size_t)b * (MM * NN / 2);
        for (int sl = wid; sl < 47; sl += 4) {
            const int s    = T0 + M0 + sl;
            const int tglo = sl > 31 ? sl - 31 : 0;
            const int tghi = sl < 15 ? sl : 15;
            const int L    = tghi - tglo + 1;
            if (lane < 4 * L) {
                const int tgi = tglo + (lane >> 2);
                const int ml  = sl - tgi;
                const int c4  = lane & 3;
                uintx4 v = *(const uintx4*)&SP[tgi * 512 + ml * 16 + c4 * 4];
                unsigned int* dst = Qw + q_pre(s) * 16 + (T0 + tgi - q_tb(s)) * 16 + c4 * 4;
                *(uintx4*)dst = v;
            }
        }
    }
}

// ---------------------------------------------------------------------------
// Kernel 2: t-domain DP, hard max3. UNCHANGED (byte-identical) from the
// round-7/8-verified version (71.7us). Known issue for a later round: the
// allocator spills the prefetch buffers to LDS (LDS_Block_Size=5120 with no
// __shared__), exposing ~510cy/step — needs asm-counted-vmcnt ring.
// ---------------------------------------------------------------------------
__global__ __launch_bounds__(64, 1) void softdtw_kernel(const float* __restrict__ P,
                                                        float* __restrict__ out) {
    const int b = blockIdx.x;
    const int t = threadIdx.x;
    const unsigned int* Qu = (const unsigned int*)P + (size_t)b * (MM * NN / 2);

    uintx4 bA[4], bB[4], bC[4], bD[4];

#define LOADC(BUF, SN)                                                          \
    {                                                                           \
        int ss = (SN); ss = ss < 0 ? 0 : (ss > 190 ? 190 : ss);                 \
        const int cv = q_cnt(ss);                                               \
        int tsl = t - q_tb(ss);                                                 \
        tsl = tsl < 0 ? 0 : (tsl > cv - 1 ? cv - 1 : tsl);                      \
        const unsigned int* bp = Qu + q_pre(ss) * 16 + tsl * 16;                \
        BUF[0] = *(const uintx4*)(bp);                                          \
        BUF[1] = *(const uintx4*)(bp + 4);                                      \
        BUF[2] = *(const uintx4*)(bp + 8);                                      \
        BUF[3] = *(const uintx4*)(bp + 12);                                     \
        __builtin_amdgcn_sched_barrier(0);                                      \
    }

    LOADC(bA, 0)
    LOADC(bB, 1)
    LOADC(bC, 2)
    LOADC(bD, 3)

    float left[8], top[4], bot[4];
#pragma unroll
    for (int r = 0; r < 8; ++r) left[r] = NEGB;
#pragma unroll
    for (int k = 0; k < 4; ++k) { top[k] = NEGB; bot[k] = NEGB; }
    float tl = (t == 0) ? 0.0f : NEGB;

#define DTW_STEP(S, CUR)                                                        \
    {                                                                           \
        const int c = (S) - t;                                                  \
        if (c >= 0 && c < 128) {                                                \
            float Rt[8][4];                                                     \
            _Pragma("unroll")                                                   \
            for (int dd = 0; dd <= 10; ++dd) {                                  \
                _Pragma("unroll")                                               \
                for (int r = 0; r < 8; ++r) {                                   \
                    const int cl = dd - r;                                      \
                    if (cl < 0 || cl > 3) continue;                             \
                    float dg, up, lf;                                           \
                    if (r == 0) { dg = (cl == 0) ? tl : top[cl - 1]; up = top[cl]; } \
                    else        { dg = (cl == 0) ? left[r - 1] : Rt[r - 1][cl - 1]; up = Rt[r - 1][cl]; } \
                    lf = (cl == 0) ? left[r] : Rt[r][cl - 1];                   \
                    const int wI = cl * 4 + (r >> 1);                           \
                    const unsigned int uu = CUR[wI >> 2][wI & 3];               \
                    const float Dv = __uint_as_float((r & 1) ? (uu & 0xFFFF0000u) \
                                                             : (uu << 16));    \
                    Rt[r][cl] = fmaxf(fmaxf(dg, up), lf) + Dv;                  \
                }                                                               \
            }                                                                   \
            _Pragma("unroll")                                                   \
            for (int r = 0; r < 8; ++r) left[r] = Rt[r][3];                     \
            _Pragma("unroll")                                                   \
            for (int k = 0; k < 4; ++k) bot[k] = Rt[7][k];                      \
        }                                                                       \
        float ntl = top[3];                                                     \
        _Pragma("unroll")                                                       \
        for (int k = 0; k < 4; ++k) {                                           \
            float v = __shfl_up(bot[k], 1, 64);                                 \
            top[k] = (t == 0) ? NEGB : v;                                       \
        }                                                                       \
        tl = (t == 0) ? NEGB : ntl;                                             \
    }

    // steps 0..187 in 47 unrolled quads; each buffer reloaded 4 steps ahead
    for (int p = 0; p < 47; ++p) {
        const int s = 4 * p;
        DTW_STEP(s,     bA)
        LOADC(bA, s + 4)
        DTW_STEP(s + 1, bB)
        LOADC(bB, s + 5)
        DTW_STEP(s + 2, bC)
        LOADC(bC, s + 6)
        DTW_STEP(s + 3, bD)
        LOADC(bD, s + 7)
    }
    DTW_STEP(188, bA)
    DTW_STEP(189, bB)
    DTW_STEP(190, bC)
#undef DTW_STEP
#undef LOADC

    if (t == 63) atomicAdd(out, bot[3] * (-GLN2 / 64.0f));
}

extern "C" void kernel_launch(void* const* d_in, const int* in_sizes, int n_in,
                              void* d_out, int out_size, void* d_ws, size_t ws_size,
                              hipStream_t stream) {
    const float* x = (const float*)d_in[0];   // (64, 512, 64) fp32
    const float* y = (const float*)d_in[1];   // (64, 512, 64) fp32

    float* P = (float*)d_ws;                  // 32 MB used: step-major bf16 t-domain D

    hipMemsetAsync(d_out, 0, sizeof(float), stream);
    compute_d_kernel<<<dim3(NN / 128, MM / 128, BATCH), 256, 0, stream>>>(x, y, P);
    softdtw_kernel<<<BATCH, 64, 0, stream>>>(P, (float*)d_out);
}